// Round 5
// baseline (12094.593 us; speedup 1.0000x reference)
//
#include <hip/hip_runtime.h>
#include <math.h>

#define TSTEPS 1024
#define BATCH  512
#define HID    64
#define VOC    29
#define SOS    27
#define MASK29 0x1FFFFFFFu

#define ENC_BLOCKS 512
#define DEC_BLOCKS 256
#define NTHREADS   512

__device__ __forceinline__ float frcp(float x){ return __builtin_amdgcn_rcpf(x); }
__device__ __forceinline__ float sigmf(float x){ return frcp(1.0f + __expf(-x)); }
__device__ __forceinline__ float tanhfast(float x){ return 1.0f - 2.0f*frcp(1.0f + __expf(2.0f*x)); }

// ---------------- Encoder: 1 row/block, 512 blocks (2 blocks/CU), half-row threads ----------
__global__ __attribute__((amdgpu_flat_work_group_size(NTHREADS,NTHREADS), amdgpu_waves_per_eu(4,4)))
void enc_kernel(const float* __restrict__ x,
                const float* __restrict__ Wih0, const float* __restrict__ Whh0,
                const float* __restrict__ bih0, const float* __restrict__ bhh0,
                const float* __restrict__ Wih1, const float* __restrict__ Whh1,
                const float* __restrict__ bih1, const float* __restrict__ bhh1,
                float* __restrict__ h1g, float* __restrict__ c1g)
{
  const int tid = threadIdx.x;
  const int r   = tid >> 1;     // gate row 0..255
  const int p   = tid & 1;      // half
  const int b0  = blockIdx.x;   // one batch row

  __shared__ __align__(16) float xs[32];
  __shared__ __align__(16) float g0[256];
  __shared__ __align__(16) float h0s[HID], h1s[HID];

  float w0h[32], w1i[32], w1h[32], w0i[15];
  #pragma unroll
  for (int k=0;k<32;k++){
    w0h[k]=Whh0[r*HID+32*p+k];
    w1i[k]=Wih1[r*HID+32*p+k];
    w1h[k]=Whh1[r*HID+32*p+k];
  }
  const int cb = p*15, cn = p?14:15;
  #pragma unroll
  for (int j=0;j<15;j++) w0i[j] = (j<cn)? Wih0[r*VOC+cb+j] : 0.f;
  const float bias0 = p?0.f:(bih0[r]+bhh0[r]);
  const float bias1 = p?0.f:(bih1[r]+bhh1[r]);

  float creg = 0.f;  // c0 in tid<64 ; c1 in tid in [64,128)
  if (tid<64) h0s[tid]=0.f;
  if (tid>=64 && tid<128) h1s[tid-64]=0.f;
  if (tid>=186 && tid<189) xs[29+(tid-186)]=0.f;   // pad cols 29..31 (read*0 must not be NaN)

  const int pfc = tid-128;
  const bool ispf = (pfc>=0) && (pfc<VOC);
  if (ispf) xs[pfc] = x[(size_t)b0*VOC + pfc];   // t=0
  __syncthreads();

  for (int t=0;t<TSTEPS;t++){
    float xn=0.f;
    if (ispf && t+1<TSTEPS)
      xn = x[(size_t)(t+1)*BATCH*VOC + (size_t)b0*VOC + pfc];

    // layer0 gates (half-dot + shfl combine)
    {
      float a0=bias0,a1=0.f,a2=0.f,a3=0.f;
      #pragma unroll
      for (int j=0;j<15;j++){
        float acc = fmaf(xs[cb+j], w0i[j], (j&3)==0?a0:((j&3)==1?a1:((j&3)==2?a2:a3)));
        if ((j&3)==0) a0=acc; else if ((j&3)==1) a1=acc; else if ((j&3)==2) a2=acc; else a3=acc;
      }
      const float4* hv=(const float4*)(h0s+32*p);
      #pragma unroll
      for (int c=0;c<8;c++){
        float4 q=hv[c];
        a0=fmaf(q.x,w0h[4*c+0],a0); a1=fmaf(q.y,w0h[4*c+1],a1);
        a2=fmaf(q.z,w0h[4*c+2],a2); a3=fmaf(q.w,w0h[4*c+3],a3);
      }
      float v=(a0+a1)+(a2+a3);
      v += __shfl_xor(v,1);
      if (!p) g0[r]=v;
    }
    __syncthreads();
    if (tid<64){
      int k=tid;
      float ig=g0[k],fg=g0[64+k],gg=g0[128+k],og=g0[192+k];
      float c=sigmf(fg)*creg+sigmf(ig)*tanhfast(gg);
      creg=c; h0s[k]=sigmf(og)*tanhfast(c);
    }
    __syncthreads();
    // layer1 gates
    {
      float a0=bias1,a1=0.f,a2=0.f,a3=0.f;
      const float4* iv=(const float4*)(h0s+32*p);
      const float4* hv=(const float4*)(h1s+32*p);
      #pragma unroll
      for (int c=0;c<8;c++){
        float4 q=iv[c], w=hv[c];
        a0=fmaf(q.x,w1i[4*c+0],a0); a1=fmaf(q.y,w1i[4*c+1],a1);
        a2=fmaf(q.z,w1i[4*c+2],a2); a3=fmaf(q.w,w1i[4*c+3],a3);
        a0=fmaf(w.x,w1h[4*c+0],a0); a1=fmaf(w.y,w1h[4*c+1],a1);
        a2=fmaf(w.z,w1h[4*c+2],a2); a3=fmaf(w.w,w1h[4*c+3],a3);
      }
      float v=(a0+a1)+(a2+a3);
      v += __shfl_xor(v,1);
      if (!p) g0[r]=v;
    }
    __syncthreads();
    if (tid>=64 && tid<128){
      int k=tid-64;
      float ig=g0[k],fg=g0[64+k],gg=g0[128+k],og=g0[192+k];
      float c=sigmf(fg)*creg+sigmf(ig)*tanhfast(gg);
      creg=c; h1s[k]=sigmf(og)*tanhfast(c);
    }
    if (ispf && t+1<TSTEPS) xs[pfc]=xn;
    __syncthreads();
  }

  if (tid>=64 && tid<128){
    int k=tid-64;
    h1g[b0*HID+k]=h1s[k];
    c1g[b0*HID+k]=creg;
  }
}

// ---------------- Decoder: cooperative, quad-fused gates+act, 3 syncs/step ----------------
// thread: u=row (0/1), j=hidden, q=quarter (16-col segment). Quad butterfly-reduces gates,
// each lane applies act redundantly (c kept per-lane), q0 writes h to LDS.
__global__ __attribute__((amdgpu_flat_work_group_size(NTHREADS,NTHREADS), amdgpu_waves_per_eu(2,2)))
void dec_kernel(const float* __restrict__ h1gp, const float* __restrict__ c1gp,
                const float* __restrict__ W1ih, const float* __restrict__ W1hh,
                const float* __restrict__ b1ih, const float* __restrict__ b1hh,
                const float* __restrict__ W2ih, const float* __restrict__ W2hh,
                const float* __restrict__ b2ih, const float* __restrict__ b2hh,
                const float* __restrict__ clsW, const float* __restrict__ clsb,
                float* __restrict__ out,
                unsigned long long* __restrict__ lvl1)
{
  const int tid = threadIdx.x;
  const int u   = tid >> 8;
  const int j   = (tid >> 2) & 63;
  const int q   = tid & 3;
  const int b0  = blockIdx.x * 2;
  const unsigned grp = blockIdx.x & 15;
  const unsigned idx = blockIdx.x >> 4;

  __shared__ __align__(16) float clsW_s[VOC][68];
  __shared__ __align__(16) float clsb_s[32];
  __shared__ __align__(16) float w1iq[4*8*256];   // [(g*8+cc)*256 + (j*4+q)] lane-contiguous
  __shared__ __align__(16) float h1s[2][HID];
  __shared__ __align__(16) float h2s[2][2][HID];  // [buf][row][hid]
  __shared__ unsigned maskLDS;

  for (int i=tid;i<VOC*HID;i+=NTHREADS) clsW_s[i/HID][i%HID]=clsW[i];
  if (tid<VOC) clsb_s[tid]=clsb[tid];
  for (int i=tid;i<4*8*256;i+=NTHREADS){
    int gg=i>>11, cc=(i>>8)&7, l=i&255, jj=l>>2, qq=l&3;
    int col=qq*8+cc;
    w1iq[i] = (col<VOC)? W1ih[(gg*64+jj)*VOC+col] : 0.f;
  }

  // register weights: quads of W1hh / W2ih / W2hh (gate rows {j,64+j,128+j,192+j}, cols q*16..)
  float w1h[64], w2i[64], w2h[64];
  #pragma unroll
  for (int g=0;g<4;g++){
    const int row=g*64+j, cidx=q*16;
    #pragma unroll
    for (int c=0;c<16;c++){
      w1h[g*16+c]=W1hh[row*HID+cidx+c];
      w2i[g*16+c]=W2ih[row*HID+cidx+c];
      w2h[g*16+c]=W2hh[row*HID+cidx+c];
    }
  }
  float bs1[4], bs2[4];
  #pragma unroll
  for (int g=0;g<4;g++){
    bs1[g]=b1ih[g*64+j]+b1hh[g*64+j];
    bs2[g]=b2ih[g*64+j]+b2hh[g*64+j];
  }

  float c1 = c1gp[(b0+u)*HID+j];   // identical in all 4 quad lanes
  float c2 = 0.f;
  if (tid<128){
    int uu=tid>>6,k=tid&63;
    h1s[uu][k]=h1gp[(b0+uu)*HID+k];
    h2s[0][uu][k]=0.f;
  }
  __syncthreads();

  // initial hd1 = quad-partial of W1hh . h1
  float hd1[4];
  {
    const float4* H=(const float4*)&h1s[u][q*16];
    float4 H0=H[0],H1=H[1],H2=H[2],H3=H[3];
    #pragma unroll
    for (int g=0;g<4;g++){
      const float* w=&w1h[g*16];
      float a=0.f;
      a=fmaf(H0.x,w[0],a); a=fmaf(H0.y,w[1],a); a=fmaf(H0.z,w[2],a); a=fmaf(H0.w,w[3],a);
      a=fmaf(H1.x,w[4],a); a=fmaf(H1.y,w[5],a); a=fmaf(H1.z,w[6],a); a=fmaf(H1.w,w[7],a);
      a=fmaf(H2.x,w[8],a); a=fmaf(H2.y,w[9],a); a=fmaf(H2.z,w[10],a); a=fmaf(H2.w,w[11],a);
      a=fmaf(H3.x,w[12],a); a=fmaf(H3.y,w[13],a); a=fmaf(H3.z,w[14],a); a=fmaf(H3.w,w[15],a);
      hd1[g]=a;
    }
  }

  unsigned mask = 1u<<SOS;

  for (int s=0;s<TSTEPS;s++){
    const int rb = s&1, wb = rb^1;

    // ---- Stage A: cell1 gates + act (fused) ----
    {
      const unsigned mq = (mask>>(q*8)) & 0xFFu;
      float gv[4];
      #pragma unroll
      for (int g=0;g<4;g++){
        float a = hd1[g] + (q==0 ? bs1[g] : 0.f);
        #pragma unroll
        for (int cc=0;cc<8;cc++){
          float w = w1iq[((g*8+cc)<<8) + (tid&255)];
          a += ((mq>>cc)&1u) ? w : 0.f;
        }
        gv[g]=a;
      }
      #pragma unroll
      for (int g=0;g<4;g++){ gv[g]+=__shfl_xor(gv[g],1); gv[g]+=__shfl_xor(gv[g],2); }
      float ig=sigmf(gv[0]), fg=sigmf(gv[1]), gg=tanhfast(gv[2]), og=sigmf(gv[3]);
      c1 = fg*c1 + ig*gg;
      float h = og*tanhfast(c1);
      if (q==0) h1s[u][j]=h;
    }
    __syncthreads();

    // ---- Stage B: cell2 gates + act (fused) ----
    {
      const float4* A=(const float4*)&h1s[u][q*16];
      const float4* B=(const float4*)&h2s[rb][u][q*16];
      float4 A0=A[0],A1=A[1],A2=A[2],A3=A[3];
      float4 B0=B[0],B1=B[1],B2=B[2],B3=B[3];
      float gv[4];
      #pragma unroll
      for (int g=0;g<4;g++){
        const float* wi=&w2i[g*16];
        const float* wh=&w2h[g*16];
        float a = (q==0 ? bs2[g] : 0.f);
        a=fmaf(A0.x,wi[0],a); a=fmaf(A0.y,wi[1],a); a=fmaf(A0.z,wi[2],a); a=fmaf(A0.w,wi[3],a);
        a=fmaf(A1.x,wi[4],a); a=fmaf(A1.y,wi[5],a); a=fmaf(A1.z,wi[6],a); a=fmaf(A1.w,wi[7],a);
        a=fmaf(A2.x,wi[8],a); a=fmaf(A2.y,wi[9],a); a=fmaf(A2.z,wi[10],a); a=fmaf(A2.w,wi[11],a);
        a=fmaf(A3.x,wi[12],a); a=fmaf(A3.y,wi[13],a); a=fmaf(A3.z,wi[14],a); a=fmaf(A3.w,wi[15],a);
        a=fmaf(B0.x,wh[0],a); a=fmaf(B0.y,wh[1],a); a=fmaf(B0.z,wh[2],a); a=fmaf(B0.w,wh[3],a);
        a=fmaf(B1.x,wh[4],a); a=fmaf(B1.y,wh[5],a); a=fmaf(B1.z,wh[6],a); a=fmaf(B1.w,wh[7],a);
        a=fmaf(B2.x,wh[8],a); a=fmaf(B2.y,wh[9],a); a=fmaf(B2.z,wh[10],a); a=fmaf(B2.w,wh[11],a);
        a=fmaf(B3.x,wh[12],a); a=fmaf(B3.y,wh[13],a); a=fmaf(B3.z,wh[14],a); a=fmaf(B3.w,wh[15],a);
        gv[g]=a;
      }
      #pragma unroll
      for (int g=0;g<4;g++){ gv[g]+=__shfl_xor(gv[g],1); gv[g]+=__shfl_xor(gv[g],2); }
      float ig=sigmf(gv[0]), fg=sigmf(gv[1]), gg=tanhfast(gv[2]), og=sigmf(gv[3]);
      c2 = fg*c2 + ig*gg;
      float h = og*tanhfast(c2);
      if (q==0) h2s[wb][u][j]=h;
    }
    __syncthreads();

    // ---- Stage C: classifier + argmax + RMW (wave0), hd1 precompute (all), poll ----
    if (tid<64){
      int row=tid>>5, v=tid&31;
      float pv=-INFINITY;
      if (v<VOC){
        float a0=clsb_s[v],a1=0.f,a2=0.f,a3=0.f;
        const float4* h4=(const float4*)h2s[wb][row];
        #pragma unroll
        for (int c=0;c<16;c++){
          float4 qq=h4[c];
          a0=fmaf(qq.x,clsW_s[v][4*c+0],a0); a1=fmaf(qq.y,clsW_s[v][4*c+1],a1);
          a2=fmaf(qq.z,clsW_s[v][4*c+2],a2); a3=fmaf(qq.w,clsW_s[v][4*c+3],a3);
        }
        pv=(a0+a1)+(a2+a3);
        out[((size_t)s*BATCH + (size_t)(b0+row))*VOC + v]=pv;
      }
      int ix=v;
      #pragma unroll
      for (int off=16; off>0; off>>=1){
        float ov=__shfl_xor(pv,off);
        int   oi=__shfl_xor(ix,off);
        if (ov>pv || (ov==pv && oi<ix)){ pv=ov; ix=oi; }
      }
      unsigned bit = 1u<<ix;
      unsigned mb  = bit | __shfl_xor(bit,32);
      if (tid==0 && s+1<TSTEPS)
        __hip_atomic_fetch_or(&lvl1[(size_t)grp*TSTEPS+s],
                              (unsigned long long)mb | (1ULL<<(32+idx)),
                              __ATOMIC_RELAXED, __HIP_MEMORY_SCOPE_AGENT);
    }
    // hd1 for next step (uses h1s written this step; stable through C)
    {
      const float4* H=(const float4*)&h1s[u][q*16];
      float4 H0=H[0],H1=H[1],H2=H[2],H3=H[3];
      #pragma unroll
      for (int g=0;g<4;g++){
        const float* w=&w1h[g*16];
        float a=0.f;
        a=fmaf(H0.x,w[0],a); a=fmaf(H0.y,w[1],a); a=fmaf(H0.z,w[2],a); a=fmaf(H0.w,w[3],a);
        a=fmaf(H1.x,w[4],a); a=fmaf(H1.y,w[5],a); a=fmaf(H1.z,w[6],a); a=fmaf(H1.w,w[7],a);
        a=fmaf(H2.x,w[8],a); a=fmaf(H2.y,w[9],a); a=fmaf(H2.z,w[10],a); a=fmaf(H2.w,w[11],a);
        a=fmaf(H3.x,w[12],a); a=fmaf(H3.y,w[13],a); a=fmaf(H3.z,w[14],a); a=fmaf(H3.w,w[15],a);
        hd1[g]=a;
      }
    }
    if (s+1<TSTEPS){
      if (tid<64){
        while (true){
          unsigned long long u64 = 0;
          if (tid<16)
            u64 = __hip_atomic_load(&lvl1[(size_t)tid*TSTEPS+s],
                                    __ATOMIC_RELAXED, __HIP_MEMORY_SCOPE_AGENT);
          bool ok = (tid>=16) || ((unsigned)(u64>>32) == 0xFFFFu);
          if (__ballot(ok) == ~0ull){
            unsigned m = (tid<16) ? ((unsigned)u64 & MASK29) : 0u;
            m |= __shfl_xor(m,1); m |= __shfl_xor(m,2);
            m |= __shfl_xor(m,4); m |= __shfl_xor(m,8);
            if (tid==0) maskLDS = m;
            break;
          }
        }
      }
      __syncthreads();
      mask = maskLDS;
    }
  }
}

extern "C" void kernel_launch(void* const* d_in, const int* in_sizes, int n_in,
                              void* d_out, int out_size, void* d_ws, size_t ws_size,
                              hipStream_t stream)
{
  const float* x     = (const float*)d_in[0];
  const float* eWih0 = (const float*)d_in[1];
  const float* eWhh0 = (const float*)d_in[2];
  const float* ebih0 = (const float*)d_in[3];
  const float* ebhh0 = (const float*)d_in[4];
  const float* eWih1 = (const float*)d_in[5];
  const float* eWhh1 = (const float*)d_in[6];
  const float* ebih1 = (const float*)d_in[7];
  const float* ebhh1 = (const float*)d_in[8];
  const float* d1Wih = (const float*)d_in[9];
  const float* d1Whh = (const float*)d_in[10];
  const float* d1bih = (const float*)d_in[11];
  const float* d1bhh = (const float*)d_in[12];
  const float* d2Wih = (const float*)d_in[13];
  const float* d2Whh = (const float*)d_in[14];
  const float* d2bih = (const float*)d_in[15];
  const float* d2bhh = (const float*)d_in[16];
  const float* clsW  = (const float*)d_in[17];
  const float* clsb  = (const float*)d_in[18];
  float* out = (float*)d_out;

  float* h1g = (float*)d_ws;
  float* c1g = h1g + BATCH*HID;
  unsigned long long* lvl1 = (unsigned long long*)((char*)d_ws + (size_t)(2*BATCH*HID)*sizeof(float));

  hipMemsetAsync(lvl1, 0, 16*TSTEPS*sizeof(unsigned long long), stream);

  enc_kernel<<<ENC_BLOCKS, NTHREADS, 0, stream>>>(
      x, eWih0,eWhh0,ebih0,ebhh0, eWih1,eWhh1,ebih1,ebhh1, h1g,c1g);

  void* args[] = { (void*)&h1g, (void*)&c1g,
                   (void*)&d1Wih,(void*)&d1Whh,(void*)&d1bih,(void*)&d1bhh,
                   (void*)&d2Wih,(void*)&d2Whh,(void*)&d2bih,(void*)&d2bhh,
                   (void*)&clsW,(void*)&clsb,(void*)&out,(void*)&lvl1 };
  hipLaunchCooperativeKernel((void*)dec_kernel, dim3(DEC_BLOCKS), dim3(NTHREADS),
                             args, 0, stream);
}

// Round 6
// 7509.976 us; speedup vs baseline: 1.6105x; 1.6105x over previous
//
#include <hip/hip_runtime.h>
#include <math.h>

#define TSTEPS 1024
#define BATCH  512
#define HID    64
#define VOC    29
#define SOS    27
#define MASK29 0x1FFFFFFFu

#define ENC_BLOCKS 256
#define DEC_BLOCKS 256
#define NTHREADS   512

__device__ __forceinline__ float frcp(float x){ return __builtin_amdgcn_rcpf(x); }
__device__ __forceinline__ float sigmf(float x){ return frcp(1.0f + __expf(-x)); }
__device__ __forceinline__ float tanhfast(float x){ return 1.0f - 2.0f*frcp(1.0f + __expf(2.0f*x)); }

// lanes l=g*2+p in an oct hold gate g; after halves combined, gather all 4 gates in-wave.
// gate t lives at shfl source [v,b,c,d][g^t]  (b=xor2, c=xor4, d=xor6)
__device__ __forceinline__ void gate_gather(float v, int g, float&i, float&f, float&gg, float&o){
  float b = __shfl_xor(v,2);
  float c = __shfl_xor(v,4);
  float d = __shfl_xor(v,6);
  i  = (g==0)?v:(g==1)?b:(g==2)?c:d;
  f  = (g==1)?v:(g==0)?b:(g==3)?c:d;
  gg = (g==2)?v:(g==3)?b:(g==0)?c:d;
  o  = (g==3)?v:(g==2)?b:(g==1)?c:d;
}
__device__ __forceinline__ float lstm_act(float i,float f,float g,float o,float&c){
  c = sigmf(f)*c + sigmf(i)*tanhfast(g);
  return sigmf(o)*tanhfast(c);
}

// ---------------- Encoder: 2 rows/block, (k,g,p) threads, fused gate+act, 2 syncs/step ------
__global__ __attribute__((amdgpu_flat_work_group_size(NTHREADS,NTHREADS), amdgpu_waves_per_eu(2,2)))
void enc_kernel(const float* __restrict__ x,
                const float* __restrict__ Wih0, const float* __restrict__ Whh0,
                const float* __restrict__ bih0, const float* __restrict__ bhh0,
                const float* __restrict__ Wih1, const float* __restrict__ Whh1,
                const float* __restrict__ bih1, const float* __restrict__ bhh1,
                float* __restrict__ h1g, float* __restrict__ c1g)
{
  const int tid = threadIdx.x;
  const int k   = tid >> 3;
  const int l   = tid & 7;
  const int g   = l >> 1;
  const int p   = l & 1;
  const int b0  = blockIdx.x * 2;
  const int row = g*64 + k;

  __shared__ __align__(16) float xs[2][32];
  __shared__ __align__(16) float h0s[2][2][HID], h1s[2][2][HID];  // [buf][row][hid]

  float w0i[15], w0h[32], w1i[32], w1h[32];
  #pragma unroll
  for (int j=0;j<15;j++) w0i[j] = (p && j==14) ? 0.f : Wih0[row*VOC + p*15 + j];
  #pragma unroll
  for (int j=0;j<32;j++){
    w0h[j]=Whh0[row*HID+32*p+j];
    w1i[j]=Wih1[row*HID+32*p+j];
    w1h[j]=Whh1[row*HID+32*p+j];
  }
  const float bias0 = p?0.f:(bih0[row]+bhh0[row]);
  const float bias1 = p?0.f:(bih1[row]+bhh1[row]);

  float c0[2]={0.f,0.f}, c1[2]={0.f,0.f}, hlast[2]={0.f,0.f};
  if (tid<128){ int uu=tid>>6,kk=tid&63; h0s[1][uu][kk]=0.f; h1s[1][uu][kk]=0.f; }
  if (tid>=128 && tid<134){ int z=tid-128; xs[z>=3][29+(z%3)]=0.f; }  // zero pad cols 29..31

  const bool ispf = tid < 2*VOC;
  const int  xb   = (tid >= VOC) ? 1 : 0;
  const int  xk   = tid - xb*VOC;
  if (ispf) xs[xb][xk] = x[(size_t)(b0+xb)*VOC + xk];   // t = 0
  __syncthreads();

  for (int t=0;t<TSTEPS;t++){
    const int rb=(t&1)^1, wb=t&1;
    float xn=0.f;
    if (ispf && t+1<TSTEPS)
      xn = x[(size_t)(t+1)*BATCH*VOC + (size_t)(b0+xb)*VOC + xk];

    // ---- layer0 fused gate+act ----
    #pragma unroll
    for (int u=0;u<2;u++){
      float a0=bias0,a1=0.f,a2=0.f,a3=0.f;
      #pragma unroll
      for (int j=0;j<15;j++){
        float t0 = xs[u][p*15+j]*w0i[j];
        if ((j&3)==0) a0+=t0; else if ((j&3)==1) a1+=t0; else if ((j&3)==2) a2+=t0; else a3+=t0;
      }
      const float4* hv=(const float4*)&h0s[rb][u][32*p];
      #pragma unroll
      for (int c=0;c<8;c++){
        float4 q=hv[c];
        a0=fmaf(q.x,w0h[4*c+0],a0); a1=fmaf(q.y,w0h[4*c+1],a1);
        a2=fmaf(q.z,w0h[4*c+2],a2); a3=fmaf(q.w,w0h[4*c+3],a3);
      }
      float v=(a0+a1)+(a2+a3);
      v += __shfl_xor(v,1);
      float ig,fg,gg,og;
      gate_gather(v,g,ig,fg,gg,og);
      float h = lstm_act(ig,fg,gg,og,c0[u]);
      if (l==0) h0s[wb][u][k]=h;
    }
    __syncthreads();
    // ---- layer1 fused gate+act ----
    #pragma unroll
    for (int u=0;u<2;u++){
      float a0=bias1,a1=0.f,a2=0.f,a3=0.f;
      const float4* iv=(const float4*)&h0s[wb][u][32*p];
      const float4* hv=(const float4*)&h1s[rb][u][32*p];
      #pragma unroll
      for (int c=0;c<8;c++){
        float4 q=iv[c], w=hv[c];
        a0=fmaf(q.x,w1i[4*c+0],a0); a1=fmaf(q.y,w1i[4*c+1],a1);
        a2=fmaf(q.z,w1i[4*c+2],a2); a3=fmaf(q.w,w1i[4*c+3],a3);
        a0=fmaf(w.x,w1h[4*c+0],a0); a1=fmaf(w.y,w1h[4*c+1],a1);
        a2=fmaf(w.z,w1h[4*c+2],a2); a3=fmaf(w.w,w1h[4*c+3],a3);
      }
      float v=(a0+a1)+(a2+a3);
      v += __shfl_xor(v,1);
      float ig,fg,gg,og;
      gate_gather(v,g,ig,fg,gg,og);
      float h = lstm_act(ig,fg,gg,og,c1[u]);
      hlast[u]=h;
      if (l==0) h1s[wb][u][k]=h;
    }
    if (ispf && t+1<TSTEPS) xs[xb][xk]=xn;
    __syncthreads();
  }

  if (l==0){
    #pragma unroll
    for (int u=0;u<2;u++){
      h1g[(b0+u)*HID+k]=hlast[u];
      c1g[(b0+u)*HID+k]=c1[u];
    }
  }
}

// ---------------- Decoder: cooperative, fused stages, 2 syncs/step, LDS mask-spin ----------
__global__ __attribute__((amdgpu_flat_work_group_size(NTHREADS,NTHREADS), amdgpu_waves_per_eu(2,2)))
void dec_kernel(const float* __restrict__ h1gp, const float* __restrict__ c1gp,
                const float* __restrict__ W1ih, const float* __restrict__ W1hh,
                const float* __restrict__ b1ih, const float* __restrict__ b1hh,
                const float* __restrict__ W2ih, const float* __restrict__ W2hh,
                const float* __restrict__ b2ih, const float* __restrict__ b2hh,
                const float* __restrict__ clsW, const float* __restrict__ clsb,
                float* __restrict__ out,
                unsigned long long* __restrict__ lvl1)
{
  const int tid = threadIdx.x;
  const int k   = tid >> 3;
  const int l   = tid & 7;
  const int g   = l >> 1;
  const int p   = l & 1;
  const int b0  = blockIdx.x * 2;
  const unsigned grp = blockIdx.x & 31;   // 32 groups x 8 blocks
  const unsigned idx = blockIdx.x >> 5;   // 0..7
  const int row = g*64 + k;

  __shared__ __align__(16) float clsW_s[VOC][68];
  __shared__ __align__(16) float clsb_s[32];
  __shared__ __align__(16) float h1s[2][2][HID], h2s[2][2][HID];
  __shared__ unsigned mask2;

  for (int i=tid;i<VOC*HID;i+=NTHREADS) clsW_s[i/HID][i%HID]=clsW[i];
  if (tid<VOC) clsb_s[tid]=clsb[tid];
  if (tid==0) __hip_atomic_store(&mask2, 0u, __ATOMIC_RELAXED, __HIP_MEMORY_SCOPE_WORKGROUP);

  float wi1c[15], w1h[32], w2i[32], w2h[32];
  #pragma unroll
  for (int j=0;j<15;j++) wi1c[j] = (p && j==14) ? 0.f : W1ih[row*VOC + p*15 + j];
  #pragma unroll
  for (int j=0;j<32;j++){
    w1h[j]=W1hh[row*HID+32*p+j];
    w2i[j]=W2ih[row*HID+32*p+j];
    w2h[j]=W2hh[row*HID+32*p+j];
  }
  const float bs1 = p?0.f:(b1ih[row]+b1hh[row]);
  const float bs2 = p?0.f:(b2ih[row]+b2hh[row]);

  float c1[2], c2[2]={0.f,0.f};
  #pragma unroll
  for (int u=0;u<2;u++) c1[u] = c1gp[(b0+u)*HID+k];
  if (tid<128){
    int uu=tid>>6,kk=tid&63;
    h1s[1][uu][kk]=h1gp[(b0+uu)*HID+kk];
    h2s[1][uu][kk]=0.f;
  }
  __syncthreads();

  float hd1[2];
  #pragma unroll
  for (int u=0;u<2;u++){
    float a0=0.f,a1=0.f,a2=0.f,a3=0.f;
    const float4* hv=(const float4*)&h1s[1][u][32*p];
    #pragma unroll
    for (int c=0;c<8;c++){
      float4 q=hv[c];
      a0=fmaf(q.x,w1h[4*c+0],a0); a1=fmaf(q.y,w1h[4*c+1],a1);
      a2=fmaf(q.z,w1h[4*c+2],a2); a3=fmaf(q.w,w1h[4*c+3],a3);
    }
    hd1[u]=(a0+a1)+(a2+a3);
  }

  unsigned mask = 1u<<SOS;

  for (int s=0;s<TSTEPS;s++){
    const int wb=s&1, rb2=wb^1;

    // ---- Stage A: cell1 fused (pure registers) ----
    #pragma unroll
    for (int u=0;u<2;u++){
      float v = hd1[u] + bs1;
      #pragma unroll
      for (int j=0;j<15;j++)
        v += ((mask>>(p*15+j))&1u) ? wi1c[j] : 0.f;
      v += __shfl_xor(v,1);
      float ig,fg,gg,og;
      gate_gather(v,g,ig,fg,gg,og);
      float h = lstm_act(ig,fg,gg,og,c1[u]);
      if (l==0) h1s[wb][u][k]=h;
    }
    __syncthreads();

    // ---- Stage B: cell2 fused ----
    #pragma unroll
    for (int u=0;u<2;u++){
      float a0=bs2,a1=0.f,a2=0.f,a3=0.f;
      const float4* iv=(const float4*)&h1s[wb][u][32*p];
      const float4* hv=(const float4*)&h2s[rb2][u][32*p];
      #pragma unroll
      for (int c=0;c<8;c++){
        float4 q=iv[c], w=hv[c];
        a0=fmaf(q.x,w2i[4*c+0],a0); a1=fmaf(q.y,w2i[4*c+1],a1);
        a2=fmaf(q.z,w2i[4*c+2],a2); a3=fmaf(q.w,w2i[4*c+3],a3);
        a0=fmaf(w.x,w2h[4*c+0],a0); a1=fmaf(w.y,w2h[4*c+1],a1);
        a2=fmaf(w.z,w2h[4*c+2],a2); a3=fmaf(w.w,w2h[4*c+3],a3);
      }
      float v=(a0+a1)+(a2+a3);
      v += __shfl_xor(v,1);
      float ig,fg,gg,og;
      gate_gather(v,g,ig,fg,gg,og);
      float h = lstm_act(ig,fg,gg,og,c2[u]);
      if (l==0) h2s[wb][u][k]=h;
    }
    __syncthreads();

    // ---- Stage C: cls/argmax/RMW (wave0) + hd1 precompute (all) + mask delivery ----
    if (tid<64){
      int row2=tid>>5, v2=tid&31;
      float pv=-INFINITY;
      if (v2<VOC){
        float a0=clsb_s[v2],a1=0.f,a2=0.f,a3=0.f;
        const float4* h4=(const float4*)h2s[wb][row2];
        #pragma unroll
        for (int c=0;c<16;c++){
          float4 q=h4[c];
          a0=fmaf(q.x,clsW_s[v2][4*c+0],a0); a1=fmaf(q.y,clsW_s[v2][4*c+1],a1);
          a2=fmaf(q.z,clsW_s[v2][4*c+2],a2); a3=fmaf(q.w,clsW_s[v2][4*c+3],a3);
        }
        pv=(a0+a1)+(a2+a3);
        out[((size_t)s*BATCH + (size_t)(b0+row2))*VOC + v2]=pv;
      }
      int ix=v2;
      #pragma unroll
      for (int off=16; off>0; off>>=1){
        float ov=__shfl_xor(pv,off);
        int   oi=__shfl_xor(ix,off);
        if (ov>pv || (ov==pv && oi<ix)){ pv=ov; ix=oi; }
      }
      unsigned bit = 1u<<ix;
      unsigned mb  = bit | __shfl_xor(bit,32);
      if (tid==0 && s+1<TSTEPS)
        __hip_atomic_fetch_or(&lvl1[(size_t)grp*TSTEPS+s],
                              (unsigned long long)mb | (1ULL<<(32+idx)),
                              __ATOMIC_RELAXED, __HIP_MEMORY_SCOPE_AGENT);
    }
    // hd1 for next step (reads h1s[wb], safe: A(s+1) writes the other buffer)
    #pragma unroll
    for (int u=0;u<2;u++){
      float a0=0.f,a1=0.f,a2=0.f,a3=0.f;
      const float4* hv=(const float4*)&h1s[wb][u][32*p];
      #pragma unroll
      for (int c=0;c<8;c++){
        float4 q=hv[c];
        a0=fmaf(q.x,w1h[4*c+0],a0); a1=fmaf(q.y,w1h[4*c+1],a1);
        a2=fmaf(q.z,w1h[4*c+2],a2); a3=fmaf(q.w,w1h[4*c+3],a3);
      }
      hd1[u]=(a0+a1)+(a2+a3);
    }
    if (s+1<TSTEPS){
      const unsigned tag = (unsigned)((s&1)+1);
      if (tid<64){
        // wave0: poll the 32 group words lane-parallel
        unsigned m;
        while (true){
          unsigned long long u64 =
            __hip_atomic_load(&lvl1[(size_t)(tid&31)*TSTEPS+s],
                              __ATOMIC_RELAXED, __HIP_MEMORY_SCOPE_AGENT);
          bool ok = ((unsigned)(u64>>32) == 0xFFu);
          if (__ballot(ok) == ~0ull){
            m = (unsigned)u64 & MASK29;
            m |= __shfl_xor(m,1);  m |= __shfl_xor(m,2);
            m |= __shfl_xor(m,4);  m |= __shfl_xor(m,8);
            m |= __shfl_xor(m,16);
            break;
          }
          __builtin_amdgcn_s_sleep(1);
        }
        mask = m;
        if (tid==0)
          __hip_atomic_store(&mask2, m | (tag<<29),
                             __ATOMIC_RELAXED, __HIP_MEMORY_SCOPE_WORKGROUP);
      } else {
        unsigned val;
        do {
          __builtin_amdgcn_s_sleep(1);
          val = __hip_atomic_load(&mask2, __ATOMIC_RELAXED, __HIP_MEMORY_SCOPE_WORKGROUP);
        } while ((val>>29) != tag);
        mask = val & MASK29;
      }
    }
  }
}

extern "C" void kernel_launch(void* const* d_in, const int* in_sizes, int n_in,
                              void* d_out, int out_size, void* d_ws, size_t ws_size,
                              hipStream_t stream)
{
  const float* x     = (const float*)d_in[0];
  const float* eWih0 = (const float*)d_in[1];
  const float* eWhh0 = (const float*)d_in[2];
  const float* ebih0 = (const float*)d_in[3];
  const float* ebhh0 = (const float*)d_in[4];
  const float* eWih1 = (const float*)d_in[5];
  const float* eWhh1 = (const float*)d_in[6];
  const float* ebih1 = (const float*)d_in[7];
  const float* ebhh1 = (const float*)d_in[8];
  const float* d1Wih = (const float*)d_in[9];
  const float* d1Whh = (const float*)d_in[10];
  const float* d1bih = (const float*)d_in[11];
  const float* d1bhh = (const float*)d_in[12];
  const float* d2Wih = (const float*)d_in[13];
  const float* d2Whh = (const float*)d_in[14];
  const float* d2bih = (const float*)d_in[15];
  const float* d2bhh = (const float*)d_in[16];
  const float* clsW  = (const float*)d_in[17];
  const float* clsb  = (const float*)d_in[18];
  float* out = (float*)d_out;

  float* h1g = (float*)d_ws;
  float* c1g = h1g + BATCH*HID;
  unsigned long long* lvl1 = (unsigned long long*)((char*)d_ws + (size_t)(2*BATCH*HID)*sizeof(float));

  hipMemsetAsync(lvl1, 0, 32*TSTEPS*sizeof(unsigned long long), stream);

  enc_kernel<<<ENC_BLOCKS, NTHREADS, 0, stream>>>(
      x, eWih0,eWhh0,ebih0,ebhh0, eWih1,eWhh1,ebih1,ebhh1, h1g,c1g);

  void* args[] = { (void*)&h1g, (void*)&c1g,
                   (void*)&d1Wih,(void*)&d1Whh,(void*)&d1bih,(void*)&d1bhh,
                   (void*)&d2Wih,(void*)&d2Whh,(void*)&d2bih,(void*)&d2bhh,
                   (void*)&clsW,(void*)&clsb,(void*)&out,(void*)&lvl1 };
  hipLaunchCooperativeKernel((void*)dec_kernel, dim3(DEC_BLOCKS), dim3(NTHREADS),
                             args, 0, stream);
}

// Round 7
// 6576.165 us; speedup vs baseline: 1.8392x; 1.1420x over previous
//
#include <hip/hip_runtime.h>
#include <math.h>

#define TSTEPS 1024
#define BATCH  512
#define HID    64
#define VOC    29
#define SOS    27
#define MASK29 0x1FFFFFFFu

#define ENC_BLOCKS 256
#define DEC_BLOCKS 256
#define NTHREADS   512

__device__ __forceinline__ float frcp(float x){ return __builtin_amdgcn_rcpf(x); }
__device__ __forceinline__ float sigmf(float x){ return frcp(1.0f + __expf(-x)); }
__device__ __forceinline__ float tanhfast(float x){ return 1.0f - 2.0f*frcp(1.0f + __expf(2.0f*x)); }

// ---------------- Encoder: cross-layer pipelined 2-layer LSTM, 2 rows/block (R4 verbatim) ----
// Waves 0-3 (tid<256): layer0 for step t.  Waves 4-7: layer1 for step t-1.
__global__ __attribute__((amdgpu_flat_work_group_size(NTHREADS,NTHREADS), amdgpu_waves_per_eu(2,2)))
void enc_kernel(const float* __restrict__ x,
                const float* __restrict__ Wih0, const float* __restrict__ Whh0,
                const float* __restrict__ bih0, const float* __restrict__ bhh0,
                const float* __restrict__ Wih1, const float* __restrict__ Whh1,
                const float* __restrict__ bih1, const float* __restrict__ bhh1,
                float* __restrict__ h1g, float* __restrict__ c1g)
{
  const int tid = threadIdx.x;
  const int b0  = blockIdx.x * 2;
  const bool g0 = tid < 256;
  const int  r  = g0 ? tid : (tid-256);

  __shared__ __align__(16) float xs[2][32];
  __shared__ __align__(16) float h0s[2][HID], h1s[2][HID];
  __shared__ __align__(16) float gA[2][256], gB[2][256];

  float wh[64], w2[64];
  if (g0){
    #pragma unroll
    for (int k=0;k<64;k++) wh[k] = Whh0[r*64+k];
    #pragma unroll
    for (int k=0;k<29;k++) w2[k] = Wih0[r*29+k];
    #pragma unroll
    for (int k=29;k<64;k++) w2[k] = 0.f;
  } else {
    #pragma unroll
    for (int k=0;k<64;k++){ wh[k] = Whh1[r*64+k]; w2[k] = Wih1[r*64+k]; }
  }
  const float bias = g0 ? (bih0[r]+bhh0[r]) : (bih1[r]+bhh1[r]);

  float creg = 0.f;
  if (tid < 128){ int u=tid>>6,k=tid&63; h0s[u][k]=0.f; h1s[u][k]=0.f; }

  const int pidx = tid - 448;
  const bool pf  = (pidx >= 0) && (pidx < 2*VOC);
  const int prow = pf ? (pidx/VOC) : 0;
  const int pcol = pf ? (pidx%VOC) : 0;
  if (pf) xs[prow][pcol] = x[(size_t)(b0+prow)*VOC + pcol];   // t=0
  __syncthreads();

  for (int t=0;t<=TSTEPS;t++){
    float xv = 0.f;
    if (pf && t+1 < TSTEPS)
      xv = x[(size_t)(t+1)*BATCH*VOC + (size_t)(b0+prow)*VOC + pcol];

    if (g0){
      if (t < TSTEPS){
        #pragma unroll
        for (int u=0;u<2;u++){
          float a0=bias,a1=0.f,a2=0.f,a3=0.f;
          const float4* xv4 = (const float4*)xs[u];
          #pragma unroll
          for (int c=0;c<7;c++){
            float4 q=xv4[c];
            a0=fmaf(q.x,w2[4*c+0],a0); a1=fmaf(q.y,w2[4*c+1],a1);
            a2=fmaf(q.z,w2[4*c+2],a2); a3=fmaf(q.w,w2[4*c+3],a3);
          }
          a0=fmaf(xs[u][28],w2[28],a0);
          const float4* h4=(const float4*)h0s[u];
          #pragma unroll
          for (int c=0;c<16;c++){
            float4 q=h4[c];
            a0=fmaf(q.x,wh[4*c+0],a0); a1=fmaf(q.y,wh[4*c+1],a1);
            a2=fmaf(q.z,wh[4*c+2],a2); a3=fmaf(q.w,wh[4*c+3],a3);
          }
          gA[u][r]=(a0+a1)+(a2+a3);
        }
      }
    } else {
      if (t >= 1){
        #pragma unroll
        for (int u=0;u<2;u++){
          float a0=bias,a1=0.f,a2=0.f,a3=0.f;
          const float4* i4=(const float4*)h0s[u];
          const float4* h4=(const float4*)h1s[u];
          #pragma unroll
          for (int c=0;c<16;c++){
            float4 q=i4[c], w=h4[c];
            a0=fmaf(q.x,w2[4*c+0],a0); a1=fmaf(q.y,w2[4*c+1],a1);
            a2=fmaf(q.z,w2[4*c+2],a2); a3=fmaf(q.w,w2[4*c+3],a3);
            a0=fmaf(w.x,wh[4*c+0],a0); a1=fmaf(w.y,wh[4*c+1],a1);
            a2=fmaf(w.z,wh[4*c+2],a2); a3=fmaf(w.w,wh[4*c+3],a3);
          }
          gB[u][r]=(a0+a1)+(a2+a3);
        }
      }
    }
    __syncthreads();
    if (tid < 128){
      if (t < TSTEPS){
        int u=tid>>6,k=tid&63;
        float ig=gA[u][k],fg=gA[u][64+k],gg=gA[u][128+k],og=gA[u][192+k];
        float c=sigmf(fg)*creg + sigmf(ig)*tanhfast(gg);
        creg=c; h0s[u][k]=sigmf(og)*tanhfast(c);
      }
    } else if (tid < 384){
      if (t >= 1){
        int tt=tid-256,u=tt>>6,k=tt&63;
        float ig=gB[u][k],fg=gB[u][64+k],gg=gB[u][128+k],og=gB[u][192+k];
        float c=sigmf(fg)*creg + sigmf(ig)*tanhfast(gg);
        creg=c; h1s[u][k]=sigmf(og)*tanhfast(c);
      }
    }
    if (pf && t+1 < TSTEPS) xs[prow][pcol] = xv;
    __syncthreads();
  }

  if (tid >= 256 && tid < 384){
    int tt=tid-256,u=tt>>6,k=tt&63;
    h1g[(b0+u)*HID+k]=h1s[u][k];
    c1g[(b0+u)*HID+k]=creg;
  }
}

// ---------------- Decoder: oct layout, l==0-only act, 3 syncs/step, R4 barrier ----------
// tid = (k<<3)|l, l=g*2+p: thread computes half-p of gate-row g*64+k.
__global__ __attribute__((amdgpu_flat_work_group_size(NTHREADS,NTHREADS), amdgpu_waves_per_eu(2,2)))
void dec_kernel(const float* __restrict__ h1gp, const float* __restrict__ c1gp,
                const float* __restrict__ W1ih, const float* __restrict__ W1hh,
                const float* __restrict__ b1ih, const float* __restrict__ b1hh,
                const float* __restrict__ W2ih, const float* __restrict__ W2hh,
                const float* __restrict__ b2ih, const float* __restrict__ b2hh,
                const float* __restrict__ clsW, const float* __restrict__ clsb,
                float* __restrict__ out,
                unsigned long long* __restrict__ lvl1)
{
  const int tid = threadIdx.x;
  const int k   = tid >> 3;
  const int l   = tid & 7;
  const int g   = l >> 1;
  const int p   = l & 1;
  const int b0  = blockIdx.x * 2;
  const unsigned grp = blockIdx.x & 15;   // 16 groups x 16 blocks (R4 topology)
  const unsigned idx = blockIdx.x >> 4;   // 0..15
  const int row = g*64 + k;

  __shared__ __align__(16) float clsW_s[VOC][68];
  __shared__ __align__(16) float clsb_s[32];
  __shared__ __align__(16) float h1s[2][2][HID], h2s[2][2][HID];  // [buf][row][hid]
  __shared__ unsigned maskLDS;

  for (int i=tid;i<VOC*HID;i+=NTHREADS) clsW_s[i/HID][i%HID]=clsW[i];
  if (tid<VOC) clsb_s[tid]=clsb[tid];

  float wi1c[15], w1h[32], w2i[32], w2h[32];
  #pragma unroll
  for (int j=0;j<15;j++) wi1c[j] = (p && j==14) ? 0.f : W1ih[row*VOC + p*15 + j];
  #pragma unroll
  for (int j=0;j<32;j++){
    w1h[j]=W1hh[row*HID+32*p+j];
    w2i[j]=W2ih[row*HID+32*p+j];
    w2h[j]=W2hh[row*HID+32*p+j];
  }
  const float bs1 = p?0.f:(b1ih[row]+b1hh[row]);
  const float bs2 = p?0.f:(b2ih[row]+b2hh[row]);

  float c1[2], c2[2]={0.f,0.f};
  #pragma unroll
  for (int u=0;u<2;u++) c1[u] = c1gp[(b0+u)*HID+k];
  if (tid<128){
    int uu=tid>>6,kk=tid&63;
    h1s[1][uu][kk]=h1gp[(b0+uu)*HID+kk];
    h2s[1][uu][kk]=0.f;
  }
  __syncthreads();

  float hd1[2];
  #pragma unroll
  for (int u=0;u<2;u++){
    float a0=0.f,a1=0.f,a2=0.f,a3=0.f;
    const float4* hv=(const float4*)&h1s[1][u][32*p];
    #pragma unroll
    for (int c=0;c<8;c++){
      float4 q=hv[c];
      a0=fmaf(q.x,w1h[4*c+0],a0); a1=fmaf(q.y,w1h[4*c+1],a1);
      a2=fmaf(q.z,w1h[4*c+2],a2); a3=fmaf(q.w,w1h[4*c+3],a3);
    }
    hd1[u]=(a0+a1)+(a2+a3);
  }

  unsigned mask = 1u<<SOS;

  for (int s=0;s<TSTEPS;s++){
    const int wb=s&1, rb=wb^1;

    // ---- Stage A: cell1 (pure registers); act on l==0 only ----
    #pragma unroll
    for (int u=0;u<2;u++){
      float v = hd1[u] + bs1;
      #pragma unroll
      for (int j=0;j<15;j++)
        v += ((mask>>(p*15+j))&1u) ? wi1c[j] : 0.f;
      v += __shfl_xor(v,1);          // combine halves: lanes 2g,2g+1 hold gate g
      float fv = __shfl_xor(v,2);    // l==0 reads gate1 (from lane 2)
      float gv = __shfl_xor(v,4);    // gate2 (lane 4)
      float ov = __shfl_xor(v,6);    // gate3 (lane 6)
      if (l==0){
        float c=sigmf(fv)*c1[u] + sigmf(v)*tanhfast(gv);
        c1[u]=c;
        h1s[wb][u][k]=sigmf(ov)*tanhfast(c);
      }
    }
    __syncthreads();

    // ---- Stage B: cell2; act on l==0 only ----
    #pragma unroll
    for (int u=0;u<2;u++){
      float a0=bs2,a1=0.f,a2=0.f,a3=0.f;
      const float4* iv=(const float4*)&h1s[wb][u][32*p];
      const float4* hv=(const float4*)&h2s[rb][u][32*p];
      #pragma unroll
      for (int c=0;c<8;c++){
        float4 q=iv[c], w=hv[c];
        a0=fmaf(q.x,w2i[4*c+0],a0); a1=fmaf(q.y,w2i[4*c+1],a1);
        a2=fmaf(q.z,w2i[4*c+2],a2); a3=fmaf(q.w,w2i[4*c+3],a3);
        a0=fmaf(w.x,w2h[4*c+0],a0); a1=fmaf(w.y,w2h[4*c+1],a1);
        a2=fmaf(w.z,w2h[4*c+2],a2); a3=fmaf(w.w,w2h[4*c+3],a3);
      }
      float v=(a0+a1)+(a2+a3);
      v += __shfl_xor(v,1);
      float fv = __shfl_xor(v,2);
      float gv = __shfl_xor(v,4);
      float ov = __shfl_xor(v,6);
      if (l==0){
        float c=sigmf(fv)*c2[u] + sigmf(v)*tanhfast(gv);
        c2[u]=c;
        h2s[wb][u][k]=sigmf(ov)*tanhfast(c);
      }
    }
    __syncthreads();

    // ---- Stage C: cls/argmax/RMW (wave0); hd1 precompute (all); poll; deliver ----
    if (tid<64){
      int row2=tid>>5, v2=tid&31;
      float pv=-INFINITY;
      if (v2<VOC){
        float a0=clsb_s[v2],a1=0.f,a2=0.f,a3=0.f;
        const float4* h4=(const float4*)h2s[wb][row2];
        #pragma unroll
        for (int c=0;c<16;c++){
          float4 q=h4[c];
          a0=fmaf(q.x,clsW_s[v2][4*c+0],a0); a1=fmaf(q.y,clsW_s[v2][4*c+1],a1);
          a2=fmaf(q.z,clsW_s[v2][4*c+2],a2); a3=fmaf(q.w,clsW_s[v2][4*c+3],a3);
        }
        pv=(a0+a1)+(a2+a3);
        out[((size_t)s*BATCH + (size_t)(b0+row2))*VOC + v2]=pv;
      }
      int ix=v2;
      #pragma unroll
      for (int off=16; off>0; off>>=1){
        float ov=__shfl_xor(pv,off);
        int   oi=__shfl_xor(ix,off);
        if (ov>pv || (ov==pv && oi<ix)){ pv=ov; ix=oi; }
      }
      unsigned bit = 1u<<ix;
      unsigned mb  = bit | __shfl_xor(bit,32);
      if (tid==0 && s+1<TSTEPS)
        __hip_atomic_fetch_or(&lvl1[(size_t)grp*TSTEPS+s],
                              (unsigned long long)mb | (1ULL<<(32+idx)),
                              __ATOMIC_RELAXED, __HIP_MEMORY_SCOPE_AGENT);
    }
    // hd1 for next step (reads h1s[wb]; next A writes the other buffer)
    #pragma unroll
    for (int u=0;u<2;u++){
      float a0=0.f,a1=0.f,a2=0.f,a3=0.f;
      const float4* hv=(const float4*)&h1s[wb][u][32*p];
      #pragma unroll
      for (int c=0;c<8;c++){
        float4 q=hv[c];
        a0=fmaf(q.x,w1h[4*c+0],a0); a1=fmaf(q.y,w1h[4*c+1],a1);
        a2=fmaf(q.z,w1h[4*c+2],a2); a3=fmaf(q.w,w1h[4*c+3],a3);
      }
      hd1[u]=(a0+a1)+(a2+a3);
    }
    if (s+1<TSTEPS){
      if (tid<64){
        while (true){
          unsigned long long u64 = 0;
          if (tid<16)
            u64 = __hip_atomic_load(&lvl1[(size_t)tid*TSTEPS+s],
                                    __ATOMIC_RELAXED, __HIP_MEMORY_SCOPE_AGENT);
          bool ok = (tid>=16) || ((unsigned)(u64>>32) == 0xFFFFu);
          if (__ballot(ok) == ~0ull){
            unsigned m = (tid<16) ? ((unsigned)u64 & MASK29) : 0u;
            m |= __shfl_xor(m,1); m |= __shfl_xor(m,2);
            m |= __shfl_xor(m,4); m |= __shfl_xor(m,8);
            if (tid==0) maskLDS = m;
            break;
          }
          __builtin_amdgcn_s_sleep(1);
        }
      }
      __syncthreads();
      mask = maskLDS;
    }
  }
}

extern "C" void kernel_launch(void* const* d_in, const int* in_sizes, int n_in,
                              void* d_out, int out_size, void* d_ws, size_t ws_size,
                              hipStream_t stream)
{
  const float* x     = (const float*)d_in[0];
  const float* eWih0 = (const float*)d_in[1];
  const float* eWhh0 = (const float*)d_in[2];
  const float* ebih0 = (const float*)d_in[3];
  const float* ebhh0 = (const float*)d_in[4];
  const float* eWih1 = (const float*)d_in[5];
  const float* eWhh1 = (const float*)d_in[6];
  const float* ebih1 = (const float*)d_in[7];
  const float* ebhh1 = (const float*)d_in[8];
  const float* d1Wih = (const float*)d_in[9];
  const float* d1Whh = (const float*)d_in[10];
  const float* d1bih = (const float*)d_in[11];
  const float* d1bhh = (const float*)d_in[12];
  const float* d2Wih = (const float*)d_in[13];
  const float* d2Whh = (const float*)d_in[14];
  const float* d2bih = (const float*)d_in[15];
  const float* d2bhh = (const float*)d_in[16];
  const float* clsW  = (const float*)d_in[17];
  const float* clsb  = (const float*)d_in[18];
  float* out = (float*)d_out;

  float* h1g = (float*)d_ws;
  float* c1g = h1g + BATCH*HID;
  unsigned long long* lvl1 = (unsigned long long*)((char*)d_ws + (size_t)(2*BATCH*HID)*sizeof(float));

  hipMemsetAsync(lvl1, 0, 16*TSTEPS*sizeof(unsigned long long), stream);

  enc_kernel<<<ENC_BLOCKS, NTHREADS, 0, stream>>>(
      x, eWih0,eWhh0,ebih0,ebhh0, eWih1,eWhh1,ebih1,ebhh1, h1g,c1g);

  void* args[] = { (void*)&h1g, (void*)&c1g,
                   (void*)&d1Wih,(void*)&d1Whh,(void*)&d1bih,(void*)&d1bhh,
                   (void*)&d2Wih,(void*)&d2Whh,(void*)&d2bih,(void*)&d2bhh,
                   (void*)&clsW,(void*)&clsb,(void*)&out,(void*)&lvl1 };
  hipLaunchCooperativeKernel((void*)dec_kernel, dim3(DEC_BLOCKS), dim3(NTHREADS),
                             args, 0, stream);
}